// Round 4
// baseline (169.394 us; speedup 1.0000x reference)
//
#include <hip/hip_runtime.h>
#include <hip/hip_bf16.h>
#include <cstdint>
#include <cstddef>

#define NUM_REL    20000
#define NUM_EDGES  640000
#define DIM        128
#define NUM_HEAD   8
#define DIM_HID    16
#define NUM_BIN    10
#define CAP        128            // bucket capacity (P(overflow) ~ 4e-13)
#define CNT_STR    16             // cnt padded: 1 counter per 64B line
#define PROJ_BLKS  471            // 157 M-tiles x 3 output matrices
#define SCAT_BLKS  625            // 625*256*4 = 640000 edges, 4 per thread

using u16 = unsigned short;
using u32 = unsigned int;
typedef __attribute__((ext_vector_type(8))) short bf16x8;
typedef __attribute__((ext_vector_type(4))) float f32x4;

__device__ __forceinline__ float b2f(u16 u) { return __uint_as_float(((u32)u) << 16); }
__device__ __forceinline__ float lo2f(u32 u) { return __uint_as_float(u << 16); }
__device__ __forceinline__ float hi2f(u32 u) { return __uint_as_float(u & 0xffff0000u); }
__device__ __forceinline__ float lrelu(float x) { return fmaxf(x, 0.2f * x); }
__device__ __forceinline__ int clampi(int v, int hi) { return v < 0 ? 0 : (v > hi ? hi : v); }
__device__ __forceinline__ float ldf(const void* p, int f32m, int i)
{ return f32m ? ((const float*)p)[i] : b2f(((const u16*)p)[i]); }
__device__ __forceinline__ u16 f2b(float x)
{ u32 u = __float_as_uint(x); u += 0x7fffu + ((u >> 16) & 1u); return (u16)(u >> 16); }
__device__ __forceinline__ u32 pk2(float a, float b)
{ return (u32)f2b(a) | ((u32)f2b(b) << 16); }

// ---------------------------------------------------------------------------
// Per-block layout detection (proven logic, block-local). Deterministic
// inputs -> all blocks agree. sF[0]=is64, sF[1]=f32m.
// ---------------------------------------------------------------------------
__device__ __forceinline__ void detect_flags(const int* __restrict__ trip,
                                             const u16* __restrict__ emb,
                                             int* sF, int tid)
{
    if (tid < 64) {
        bool odd_zero = (trip[2 * tid + 1] == 0) && (trip[2 * tid + 129] == 0);
        unsigned long long m1 = __ballot(odd_zero);
        int ex = (emb[2 * tid] >> 7) & 0xFF;
        bool inr = (ex >= 110) && (ex <= 136);
        unsigned long long m2 = __ballot(inr);
        if (tid == 0) {
            sF[0] = (~m1 == 0ull) ? 1 : 0;
            sF[1] = (__popcll(m2) >= 32) ? 0 : 1;   // few in-range => fp32
        }
    }
    __syncthreads();
}

// ---------------------------------------------------------------------------
// K0: bucket scatter, isolated. 4 edges/thread, vectorized 96B (is64) or 48B
// (i32) triplet loads, 4 independent atomic chains per thread in flight.
// Isolating the 640k-atomic storm keeps it from congesting k_proj's loads.
// ---------------------------------------------------------------------------
__global__ __launch_bounds__(256) void k_scatter(
    const int* __restrict__ trip, const void* __restrict__ emb,
    int* __restrict__ cnt, int* __restrict__ bucket)
{
    __shared__ int sF[2];
    const int tid = threadIdx.x;
    detect_flags(trip, (const u16*)emb, sF, tid);
    const int is64 = sF[0];

    const int e0 = (blockIdx.x * 256 + tid) * 4;
    int h[4], t[4], b[4], p[4];
    if (is64) {
        const int4* w = (const int4*)(trip + 6 * e0);
        int4 w0 = w[0], w1 = w[1], w2 = w[2], w3 = w[3], w4 = w[4], w5 = w[5];
        h[0] = w0.x; t[0] = w0.z; b[0] = w1.x;
        h[1] = w1.z; t[1] = w2.x; b[1] = w2.z;
        h[2] = w3.x; t[2] = w3.z; b[2] = w4.x;
        h[3] = w4.z; t[3] = w5.x; b[3] = w5.z;
    } else {
        const int4* w = (const int4*)(trip + 3 * e0);
        int4 w0 = w[0], w1 = w[1], w2 = w[2];
        h[0] = w0.x; t[0] = w0.y; b[0] = w0.z;
        h[1] = w0.w; t[1] = w1.x; b[1] = w1.y;
        h[2] = w1.z; t[2] = w1.w; b[2] = w2.x;
        h[3] = w2.y; t[3] = w2.z; b[3] = w2.w;
    }
    #pragma unroll
    for (int i = 0; i < 4; ++i) {
        h[i] = clampi(h[i], NUM_REL - 1);
        t[i] = clampi(t[i], NUM_REL - 1);
        b[i] = clampi(b[i], NUM_BIN - 1);
    }
    #pragma unroll
    for (int i = 0; i < 4; ++i) p[i] = atomicAdd(&cnt[h[i] * CNT_STR], 1);
    #pragma unroll
    for (int i = 0; i < 4; ++i)
        if (p[i] < CAP) bucket[h[i] * CAP + p[i]] = t[i] | (b[i] << 20);
}

// ---------------------------------------------------------------------------
// K1: MFMA projections only (proven R2 full-K structure, 32 KB W staging).
// nt=0: A=emb@Wa1^T (fp32); nt=1: B=emb@Wa2^T+b (bf16); nt=2: M=emb@Wg^T+b.
// A-fragments read directly from global emb; W tile LDS-staged w/ XOR swizzle.
// ---------------------------------------------------------------------------
__global__ __launch_bounds__(256) void k_proj(
    const void* __restrict__ emb, const int* __restrict__ trip,
    const void* __restrict__ w_attn, const void* __restrict__ w_aggr,
    const void* __restrict__ b_attn, const void* __restrict__ b_aggr,
    float* __restrict__ A, u16* __restrict__ Bb, u16* __restrict__ Mb)
{
    __shared__ u16 sW[128 * 128];    // 32 KB
    __shared__ float sBias[128];
    __shared__ int sF[2];

    const int tid = threadIdx.x;
    detect_flags(trip, (const u16*)emb, sF, tid);
    const int f32m = sF[1];

    const int mt = blockIdx.x / 3, nt = blockIdx.x % 3;
    const int r0 = mt * 128;

    if (tid < 128)
        sBias[tid] = (nt == 0) ? 0.f : ldf((nt == 1) ? b_attn : b_aggr, f32m, tid);

    // stage W tile into LDS (XOR-chunk swizzle; conflict-free b128 reads)
    {
        const void* wsrc = (nt == 2) ? w_aggr : w_attn;
        const int stride = (nt == 2) ? 128 : 256;
        const int koff   = (nt == 1) ? 128 : 0;
        if (f32m) {
            const float* src = (const float*)wsrc;
            #pragma unroll
            for (int i = 0; i < 16; ++i) {
                int f = i * 256 + tid;
                int row = f >> 5, pos = f & 31;
                float4 x = ((const float4*)(src + (size_t)row * stride + koff))[pos];
                int chunk = (pos >> 1) ^ (row & 15);
                *(uint2*)&sW[row * 128 + chunk * 8 + (pos & 1) * 4] =
                    make_uint2(pk2(x.x, x.y), pk2(x.z, x.w));
            }
        } else {
            const u16* src = (const u16*)wsrc;
            #pragma unroll
            for (int i = 0; i < 8; ++i) {
                int f = i * 256 + tid;
                int row = f >> 4, pos = f & 15;
                uint4 x = ((const uint4*)(src + (size_t)row * stride + koff))[pos];
                int chunk = pos ^ (row & 15);
                *(uint4*)&sW[row * 128 + chunk * 8] = x;
            }
        }
    }
    __syncthreads();

    const int lane = tid & 63, wid = tid >> 6;
    const int wm = (wid >> 1) * 64, wn = (wid & 1) * 64;
    const int ln15 = lane & 15, q = lane >> 4;

    // A-frag source rows (clamped; epilogue guards the stores)
    int arow[4];
    #pragma unroll
    for (int mi = 0; mi < 4; ++mi) {
        int g = r0 + wm + mi * 16 + ln15;
        arow[mi] = (g < NUM_REL) ? g : (NUM_REL - 1);
    }

    f32x4 acc[4][4] = {};
    #pragma unroll
    for (int kk = 0; kk < 4; ++kk) {
        const int cbase = kk * 4 + q;      // chunk index = k>>3
        const int kc = cbase * 8;          // element offset within row
        bf16x8 a[4], b[4];
        #pragma unroll
        for (int mi = 0; mi < 4; ++mi) {
            if (f32m) {
                const float* er = (const float*)emb + (size_t)arow[mi] * DIM + kc;
                float4 x0 = *(const float4*)er;
                float4 x1 = *(const float4*)(er + 4);
                union { bf16x8 v; u32 u[4]; } cv;
                cv.u[0] = pk2(x0.x, x0.y); cv.u[1] = pk2(x0.z, x0.w);
                cv.u[2] = pk2(x1.x, x1.y); cv.u[3] = pk2(x1.z, x1.w);
                a[mi] = cv.v;
            } else {
                a[mi] = *(const bf16x8*)((const u16*)emb + (size_t)arow[mi] * DIM + kc);
            }
        }
        #pragma unroll
        for (int ni = 0; ni < 4; ++ni) {
            int n = wn + ni * 16 + ln15;
            int c = cbase ^ ln15;
            b[ni] = *(const bf16x8*)&sW[n * 128 + c * 8];
        }
        #pragma unroll
        for (int mi = 0; mi < 4; ++mi)
            #pragma unroll
            for (int ni = 0; ni < 4; ++ni)
                acc[mi][ni] = __builtin_amdgcn_mfma_f32_16x16x32_bf16(
                    a[mi], b[ni], acc[mi][ni], 0, 0, 0);
    }

    #pragma unroll
    for (int mi = 0; mi < 4; ++mi) {
        #pragma unroll
        for (int reg = 0; reg < 4; ++reg) {
            int g = r0 + wm + mi * 16 + q * 4 + reg;
            if (g < NUM_REL) {
                #pragma unroll
                for (int ni = 0; ni < 4; ++ni) {
                    int c = wn + ni * 16 + ln15;
                    float v = acc[mi][ni][reg] + sBias[c];
                    size_t o = (size_t)g * DIM + c;
                    if (nt == 0)      A[o]  = v;
                    else if (nt == 1) Bb[o] = f2b(v);
                    else              Mb[o] = f2b(v);
                }
            }
        }
    }
}

// ---------------------------------------------------------------------------
// K5: segment loop, software-pipelined, 16-edge tiles (2 edges per lane).
// Per tile: [distribute t, issue 16 Mb loads] -> [prefetch next tile's bucket
// entries + 2 Bb rows] -> [score: 8 interleaved FMA chains] -> [PV, 4-way
// split accumulators]. Inactive slots read row 0 and contribute 0 via p=0.
// ---------------------------------------------------------------------------
__global__ __launch_bounds__(256, 4) void k_segment(
    const float* __restrict__ A, const u16* __restrict__ Bb,
    const u16* __restrict__ Mb, const void* __restrict__ attn_bin,
    const void* __restrict__ attn_vec, const int* __restrict__ cnt,
    const int* __restrict__ bucket, const int* __restrict__ trip,
    const void* __restrict__ emb, void* __restrict__ out)
{
    __shared__ float sAr[4][DIM];
    __shared__ float sVec[DIM];
    __shared__ float sBin[NUM_BIN * NUM_HEAD];
    __shared__ int sF[2];

    const int tid  = threadIdx.x;
    detect_flags(trip, (const u16*)emb, sF, tid);
    const int f32m = sF[1];

    const int wid  = tid >> 6, lane = tid & 63;
    const int r = blockIdx.x * 4 + wid;
    int nE = cnt[r * CNT_STR]; if (nE > CAP) nE = CAP;
    const int* __restrict__ bk = bucket + r * CAP;

    {
        const float2* ap = (const float2*)(A + (size_t)r * DIM);
        float2 a2 = ap[lane];
        sAr[wid][2 * lane] = a2.x; sAr[wid][2 * lane + 1] = a2.y;
    }
    if (tid < DIM) sVec[tid] = ldf(attn_vec, f32m, tid);
    else if (tid < DIM + NUM_BIN * NUM_HEAD)
        sBin[tid - DIM] = lrelu(ldf(attn_bin, f32m, tid - DIM));
    __syncthreads();

    if (nE == 0) {
        if (f32m) ((float2*)out)[(size_t)r * 64 + lane] = make_float2(0.f, 0.f);
        else      ((u32*)out)[(size_t)r * 64 + lane] = 0;
        return;
    }

    const int el = lane >> 3, hd = lane & 7;
    const int ah = lane >> 3;              // head owning this lane's out dims

    float av[16], vv[16];
    {
        const float4* pA = (const float4*)(&sAr[wid][hd * DIM_HID]);
        const float4* pV = (const float4*)(&sVec[hd * DIM_HID]);
        #pragma unroll
        for (int i = 0; i < 4; ++i) {
            float4 a4 = pA[i], v4 = pV[i];
            av[4*i+0]=a4.x; av[4*i+1]=a4.y; av[4*i+2]=a4.z; av[4*i+3]=a4.w;
            vv[4*i+0]=v4.x; vv[4*i+1]=v4.y; vv[4*i+2]=v4.z; vv[4*i+3]=v4.w;
        }
    }

    const u16* __restrict__ Mbl = Mb + 2 * lane;

    // ---- pipeline prologue: tile-0 bucket entries + 2 Bb rows ----
    int tba = (el      < nE) ? bk[el]     : 0;
    int tbb = (8 + el  < nE) ? bk[8 + el] : 0;
    int ia = tba & 0xFFFFF, ib = tbb & 0xFFFFF;
    uint4 q0a, q1a, q0b, q1b;
    {
        const uint4* Ba = (const uint4*)(Bb + (size_t)ia * DIM) + hd * 2;
        const uint4* Bc = (const uint4*)(Bb + (size_t)ib * DIM) + hd * 2;
        q0a = Ba[0]; q1a = Ba[1];
        q0b = Bc[0]; q1b = Bc[1];
    }

    float l = 0.f;
    float ax0 = 0.f, ax1 = 0.f, ay0 = 0.f, ay1 = 0.f;

    for (int base = 0; base < nE; base += 16) {
        // ---- distribute t across lanes, issue all 16 Mb row loads ----
        u32 mm[16];
        #pragma unroll
        for (int k = 0; k < 8; ++k) {
            int tk = __shfl(ia, k * 8);
            mm[k] = *(const u32*)(Mbl + (size_t)tk * DIM);
        }
        #pragma unroll
        for (int k = 0; k < 8; ++k) {
            int tk = __shfl(ib, k * 8);
            mm[8 + k] = *(const u32*)(Mbl + (size_t)tk * DIM);
        }
        const int bsa = (tba >> 20) & 0xF;
        const int bsb = (tbb >> 20) & 0xF;

        // ---- prefetch next tile's bucket entries + Bb rows ----
        int ea_n  = base + 16 + el;
        int eb_n  = base + 24 + el;
        int tba_n = (ea_n < nE) ? bk[ea_n] : 0;
        int tbb_n = (eb_n < nE) ? bk[eb_n] : 0;
        int ia_n  = tba_n & 0xFFFFF, ib_n = tbb_n & 0xFFFFF;
        uint4 q0an, q1an, q0bn, q1bn;
        {
            const uint4* Ban = (const uint4*)(Bb + (size_t)ia_n * DIM) + hd * 2;
            const uint4* Bcn = (const uint4*)(Bb + (size_t)ib_n * DIM) + hd * 2;
            q0an = Ban[0]; q1an = Ban[1];
            q0bn = Bcn[0]; q1bn = Bcn[1];
        }

        // ---- scores: 8 interleaved FMA chains (4 per edge) ----
        float sa0 = sBin[bsa * NUM_HEAD + hd];
        float sb0 = sBin[bsb * NUM_HEAD + hd];
        sa0 = fmaf(lrelu(av[0]  + lo2f(q0a.x)), vv[0],  sa0);
        sb0 = fmaf(lrelu(av[0]  + lo2f(q0b.x)), vv[0],  sb0);
        float sa1 = lrelu(av[1] + hi2f(q0a.x)) * vv[1];
        float sb1 = lrelu(av[1] + hi2f(q0b.x)) * vv[1];
        float sa2 = lrelu(av[2] + lo2f(q0a.y)) * vv[2];
        float sb2 = lrelu(av[2] + lo2f(q0b.y)) * vv[2];
        float sa3 = lrelu(av[3] + hi2f(q0a.y)) * vv[3];
        float sb3 = lrelu(av[3] + hi2f(q0b.y)) * vv[3];
        sa0 = fmaf(lrelu(av[4]  + lo2f(q0a.z)), vv[4],  sa0);
        sb0 = fmaf(lrelu(av[4]  + lo2f(q0b.z)), vv[4],  sb0);
        sa1 = fmaf(lrelu(av[5]  + hi2f(q0a.z)), vv[5],  sa1);
        sb1 = fmaf(lrelu(av[5]  + hi2f(q0b.z)), vv[5],  sb1);
        sa2 = fmaf(lrelu(av[6]  + lo2f(q0a.w)), vv[6],  sa2);
        sb2 = fmaf(lrelu(av[6]  + lo2f(q0b.w)), vv[6],  sb2);
        sa3 = fmaf(lrelu(av[7]  + hi2f(q0a.w)), vv[7],  sa3);
        sb3 = fmaf(lrelu(av[7]  + hi2f(q0b.w)), vv[7],  sb3);
        sa0 = fmaf(lrelu(av[8]  + lo2f(q1a.x)), vv[8],  sa0);
        sb0 = fmaf(lrelu(av[8]  + lo2f(q1b.x)), vv[8],  sb0);
        sa1 = fmaf(lrelu(av[9]  + hi2f(q1a.x)), vv[9],  sa1);
        sb1 = fmaf(lrelu(av[9]  + hi2f(q1b.x)), vv[9],  sb1);
        sa2 = fmaf(lrelu(av[10] + lo2f(q1a.y)), vv[10], sa2);
        sb2 = fmaf(lrelu(av[10] + lo2f(q1b.y)), vv[10], sb2);
        sa3 = fmaf(lrelu(av[11] + hi2f(q1a.y)), vv[11], sa3);
        sb3 = fmaf(lrelu(av[11] + hi2f(q1b.y)), vv[11], sb3);
        sa0 = fmaf(lrelu(av[12] + lo2f(q1a.z)), vv[12], sa0);
        sb0 = fmaf(lrelu(av[12] + lo2f(q1b.z)), vv[12], sb0);
        sa1 = fmaf(lrelu(av[13] + hi2f(q1a.z)), vv[13], sa1);
        sb1 = fmaf(lrelu(av[13] + hi2f(q1b.z)), vv[13], sb1);
        sa2 = fmaf(lrelu(av[14] + lo2f(q1a.w)), vv[14], sa2);
        sb2 = fmaf(lrelu(av[14] + lo2f(q1b.w)), vv[14], sb2);
        sa3 = fmaf(lrelu(av[15] + hi2f(q1a.w)), vv[15], sa3);
        sb3 = fmaf(lrelu(av[15] + hi2f(q1b.w)), vv[15], sb3);
        float sa = (sa0 + sa1) + (sa2 + sa3);
        float sb = (sb0 + sb1) + (sb2 + sb3);
        sa = fminf(fmaxf(sa, -60.f), 60.f);
        sb = fminf(fmaxf(sb, -60.f), 60.f);
        float pa = ((base + el)     < nE) ? __expf(sa) : 0.f;
        float pb = ((base + 8 + el) < nE) ? __expf(sb) : 0.f;
        l += pa + pb;

        // ---- PV: 4-way split accumulators ----
        #pragma unroll
        for (int k = 0; k < 8; ++k) {
            float v = __shfl(pa, k * 8 + ah);
            if (k & 1) { ax1 = fmaf(v, lo2f(mm[k]), ax1); ay1 = fmaf(v, hi2f(mm[k]), ay1); }
            else       { ax0 = fmaf(v, lo2f(mm[k]), ax0); ay0 = fmaf(v, hi2f(mm[k]), ay0); }
        }
        #pragma unroll
        for (int k = 0; k < 8; ++k) {
            float v = __shfl(pb, k * 8 + ah);
            if (k & 1) { ax1 = fmaf(v, lo2f(mm[8+k]), ax1); ay1 = fmaf(v, hi2f(mm[8+k]), ay1); }
            else       { ax0 = fmaf(v, lo2f(mm[8+k]), ax0); ay0 = fmaf(v, hi2f(mm[8+k]), ay0); }
        }

        // ---- rotate pipeline ----
        tba = tba_n; tbb = tbb_n; ia = ia_n; ib = ib_n;
        q0a = q0an; q1a = q1an; q0b = q0bn; q1b = q1bn;
    }

    float accx = ax0 + ax1, accy = ay0 + ay1;

    float lt = l + __shfl_xor(l, 8);
    lt += __shfl_xor(lt, 16);
    lt += __shfl_xor(lt, 32);
    float lA = __shfl(lt, ah);
    float inv = 1.0f / (lA + 1e-16f);
    float o0 = accx * inv, o1 = accy * inv;
    if (f32m) {
        ((float2*)out)[(size_t)r * 64 + lane] = make_float2(o0, o1);
    } else {
        u32 pk = (u32)f2b(o0) | ((u32)f2b(o1) << 16);
        ((u32*)out)[(size_t)r * 64 + lane] = pk;
    }
}

// ---------------------------------------------------------------------------
extern "C" void kernel_launch(void* const* d_in, const int* in_sizes, int n_in,
                              void* d_out, int out_size, void* d_ws, size_t ws_size,
                              hipStream_t stream)
{
    (void)in_sizes; (void)n_in; (void)out_size; (void)ws_size;
    const void* emb      = d_in[0];
    const int*  trip     = (const int*)d_in[1];
    const void* w_attn   = d_in[2];
    const void* b_attn   = d_in[3];
    const void* attn_bin = d_in[4];
    const void* attn_vec = d_in[5];
    const void* w_aggr   = d_in[6];
    const void* b_aggr   = d_in[7];

    // workspace carve (~32.0 MB)
    char* p = (char*)d_ws;
    float* A      = (float*)p; p += (size_t)NUM_REL * DIM * 4;
    u16*   Bb     = (u16*)p;   p += (size_t)NUM_REL * DIM * 2;
    u16*   Mb     = (u16*)p;   p += (size_t)NUM_REL * DIM * 2;
    int*   bucket = (int*)p;   p += (size_t)NUM_REL * CAP * 4;
    int*   cnt    = (int*)p;   p += (size_t)NUM_REL * CNT_STR * 4;

    hipMemsetAsync(cnt, 0, (size_t)NUM_REL * CNT_STR * sizeof(int), stream);
    k_scatter<<<SCAT_BLKS, 256, 0, stream>>>(trip, emb, cnt, bucket);
    k_proj<<<PROJ_BLKS, 256, 0, stream>>>(
        emb, trip, w_attn, w_aggr, b_attn, b_aggr, A, Bb, Mb);
    k_segment<<<NUM_REL / 4, 256, 0, stream>>>(A, Bb, Mb, attn_bin, attn_vec,
                                               cnt, bucket, trip, emb, d_out);
}

// Round 5
// 163.459 us; speedup vs baseline: 1.0363x; 1.0363x over previous
//
#include <hip/hip_runtime.h>
#include <hip/hip_bf16.h>
#include <cstdint>
#include <cstddef>

#define NUM_REL    20000
#define NUM_EDGES  640000
#define DIM        128
#define NUM_HEAD   8
#define DIM_HID    16
#define NUM_BIN    10
#define CAP        128            // bucket capacity (P(overflow) ~ 4e-13)
#define CNT_STR    16             // cnt padded: 1 counter per 64B line
#define PROJ_BLKS  471            // 157 M-tiles x 3 output matrices
#define SCAT_BLKS  625            // 625*256*4 = 640000 edges, 4 per thread

using u16 = unsigned short;
using u32 = unsigned int;
typedef __attribute__((ext_vector_type(8))) short bf16x8;
typedef __attribute__((ext_vector_type(4))) float f32x4;

__device__ __forceinline__ float b2f(u16 u) { return __uint_as_float(((u32)u) << 16); }
__device__ __forceinline__ float lo2f(u32 u) { return __uint_as_float(u << 16); }
__device__ __forceinline__ float hi2f(u32 u) { return __uint_as_float(u & 0xffff0000u); }
__device__ __forceinline__ float lrelu(float x) { return fmaxf(x, 0.2f * x); }
__device__ __forceinline__ int clampi(int v, int hi) { return v < 0 ? 0 : (v > hi ? hi : v); }
__device__ __forceinline__ float ldf(const void* p, int f32m, int i)
{ return f32m ? ((const float*)p)[i] : b2f(((const u16*)p)[i]); }
__device__ __forceinline__ u16 f2b(float x)
{ u32 u = __float_as_uint(x); u += 0x7fffu + ((u >> 16) & 1u); return (u16)(u >> 16); }
__device__ __forceinline__ u32 pk2(float a, float b)
{ return (u32)f2b(a) | ((u32)f2b(b) << 16); }

// ---------------------------------------------------------------------------
// Per-block layout detection (proven logic, block-local). Deterministic
// inputs -> all blocks agree. sF[0]=is64, sF[1]=f32m.
// ---------------------------------------------------------------------------
__device__ __forceinline__ void detect_flags(const int* __restrict__ trip,
                                             const u16* __restrict__ emb,
                                             int* sF, int tid)
{
    if (tid < 64) {
        bool odd_zero = (trip[2 * tid + 1] == 0) && (trip[2 * tid + 129] == 0);
        unsigned long long m1 = __ballot(odd_zero);
        int ex = (emb[2 * tid] >> 7) & 0xFF;
        bool inr = (ex >= 110) && (ex <= 136);
        unsigned long long m2 = __ballot(inr);
        if (tid == 0) {
            sF[0] = (~m1 == 0ull) ? 1 : 0;
            sF[1] = (__popcll(m2) >= 32) ? 0 : 1;   // few in-range => fp32
        }
    }
    __syncthreads();
}

// ---------------------------------------------------------------------------
// K1: fused [MFMA projections (blocks 0..470)] || [bucket scatter (471+)].
// Split-K W staging (16 KB LDS). nt=0: A=emb@Wa1^T (fp32);
// nt=1: B-half of BM (emb@Wa2^T+b, bf16); nt=2: M-half of BM (emb@Wg^T+b).
// BM row layout: [head][16 B-dims | 16 M-dims] -> 512 B/row, one 64 B chunk
// per (row, head) serves both score and PV in k_segment.
// Scatter: 4 edges/thread, vectorized triplet loads (overlaps with proj).
// ---------------------------------------------------------------------------
__global__ __launch_bounds__(256) void k_projscatter(
    const void* __restrict__ emb, const int* __restrict__ trip,
    const void* __restrict__ w_attn, const void* __restrict__ w_aggr,
    const void* __restrict__ b_attn, const void* __restrict__ b_aggr,
    float* __restrict__ A, u16* __restrict__ BM,
    int* __restrict__ cnt, int* __restrict__ bucket)
{
    __shared__ u16 sW[128 * 64];     // 16 KB (one 64-wide K half)
    __shared__ float sBias[128];
    __shared__ int sF[2];

    const int tid = threadIdx.x;
    detect_flags(trip, (const u16*)emb, sF, tid);
    const int is64 = sF[0], f32m = sF[1];

    if (blockIdx.x >= PROJ_BLKS) {
        // ---------------- scatter: 4 edges per thread ----------------
        const int e0 = ((blockIdx.x - PROJ_BLKS) * 256 + tid) * 4;
        int h[4], t[4], b[4], p[4];
        if (is64) {
            const int4* w = (const int4*)(trip + 6 * e0);
            int4 w0 = w[0], w1 = w[1], w2 = w[2], w3 = w[3], w4 = w[4], w5 = w[5];
            h[0] = w0.x; t[0] = w0.z; b[0] = w1.x;
            h[1] = w1.z; t[1] = w2.x; b[1] = w2.z;
            h[2] = w3.x; t[2] = w3.z; b[2] = w4.x;
            h[3] = w4.z; t[3] = w5.x; b[3] = w5.z;
        } else {
            const int4* w = (const int4*)(trip + 3 * e0);
            int4 w0 = w[0], w1 = w[1], w2 = w[2];
            h[0] = w0.x; t[0] = w0.y; b[0] = w0.z;
            h[1] = w0.w; t[1] = w1.x; b[1] = w1.y;
            h[2] = w1.z; t[2] = w1.w; b[2] = w2.x;
            h[3] = w2.y; t[3] = w2.z; b[3] = w2.w;
        }
        #pragma unroll
        for (int i = 0; i < 4; ++i) {
            h[i] = clampi(h[i], NUM_REL - 1);
            t[i] = clampi(t[i], NUM_REL - 1);
            b[i] = clampi(b[i], NUM_BIN - 1);
        }
        #pragma unroll
        for (int i = 0; i < 4; ++i) p[i] = atomicAdd(&cnt[h[i] * CNT_STR], 1);
        #pragma unroll
        for (int i = 0; i < 4; ++i)
            if (p[i] < CAP) bucket[h[i] * CAP + p[i]] = t[i] | (b[i] << 20);
        return;
    }

    // ---------------- projection tile ----------------
    const int mt = blockIdx.x / 3, nt = blockIdx.x % 3;
    const int r0 = mt * 128;

    if (tid < 128)
        sBias[tid] = (nt == 0) ? 0.f : ldf((nt == 1) ? b_attn : b_aggr, f32m, tid);

    const void* wsrc = (nt == 2) ? w_aggr : w_attn;
    const int stride = (nt == 2) ? 128 : 256;
    const int koff   = (nt == 1) ? 128 : 0;

    const int lane = tid & 63, wid = tid >> 6;
    const int wm = (wid >> 1) * 64, wn = (wid & 1) * 64;
    const int ln15 = lane & 15, q = lane >> 4;

    // A-frag source rows (clamped; epilogue guards the stores)
    int arow[4];
    #pragma unroll
    for (int mi = 0; mi < 4; ++mi) {
        int g = r0 + wm + mi * 16 + ln15;
        arow[mi] = (g < NUM_REL) ? g : (NUM_REL - 1);
    }

    f32x4 acc[4][4] = {};
    #pragma unroll
    for (int kh = 0; kh < 2; ++kh) {
        if (kh) __syncthreads();      // all reads of previous half done
        // stage K-half [kh*64, kh*64+64) for all 128 output rows
        if (f32m) {
            const float* src = (const float*)wsrc;
            #pragma unroll
            for (int i = 0; i < 8; ++i) {
                int f = i * 256 + tid;
                int row = f >> 4, pos = f & 15;   // float4 index within half
                const float* rp = src + (size_t)row * stride + koff + kh * 64;
                float4 x = ((const float4*)rp)[pos];
                int chunk = (pos >> 1) ^ (row & 7);
                *(uint2*)&sW[row * 64 + chunk * 8 + (pos & 1) * 4] =
                    make_uint2(pk2(x.x, x.y), pk2(x.z, x.w));
            }
        } else {
            const u16* src = (const u16*)wsrc;
            #pragma unroll
            for (int i = 0; i < 4; ++i) {
                int f = i * 256 + tid;
                int row = f >> 3, pos = f & 7;    // uint4 index within half
                const u16* rp = src + (size_t)row * stride + koff + kh * 64;
                uint4 x = ((const uint4*)rp)[pos];
                int chunk = pos ^ (row & 7);
                *(uint4*)&sW[row * 64 + chunk * 8] = x;
            }
        }
        __syncthreads();

        #pragma unroll
        for (int k2 = 0; k2 < 2; ++k2) {
            const int kkg = kh * 2 + k2;
            const int kc = (kkg * 4 + q) * 8;         // element offset in K
            const int cl = (k2 * 4 + q) ^ (ln15 & 7); // swizzled local chunk
            bf16x8 a[4], b[4];
            #pragma unroll
            for (int mi = 0; mi < 4; ++mi) {
                if (f32m) {
                    const float* er = (const float*)emb + (size_t)arow[mi] * DIM + kc;
                    float4 x0 = *(const float4*)er;
                    float4 x1 = *(const float4*)(er + 4);
                    union { bf16x8 v; u32 u[4]; } cv;
                    cv.u[0] = pk2(x0.x, x0.y); cv.u[1] = pk2(x0.z, x0.w);
                    cv.u[2] = pk2(x1.x, x1.y); cv.u[3] = pk2(x1.z, x1.w);
                    a[mi] = cv.v;
                } else {
                    a[mi] = *(const bf16x8*)((const u16*)emb + (size_t)arow[mi] * DIM + kc);
                }
            }
            #pragma unroll
            for (int ni = 0; ni < 4; ++ni) {
                int n = wn + ni * 16 + ln15;
                b[ni] = *(const bf16x8*)&sW[n * 64 + cl * 8];
            }
            #pragma unroll
            for (int mi = 0; mi < 4; ++mi)
                #pragma unroll
                for (int ni = 0; ni < 4; ++ni)
                    acc[mi][ni] = __builtin_amdgcn_mfma_f32_16x16x32_bf16(
                        a[mi], b[ni], acc[mi][ni], 0, 0, 0);
        }
    }

    #pragma unroll
    for (int mi = 0; mi < 4; ++mi) {
        #pragma unroll
        for (int reg = 0; reg < 4; ++reg) {
            int g = r0 + wm + mi * 16 + q * 4 + reg;
            if (g < NUM_REL) {
                #pragma unroll
                for (int ni = 0; ni < 4; ++ni) {
                    int c = wn + ni * 16 + ln15;
                    float v = acc[mi][ni][reg] + sBias[c];
                    if (nt == 0) {
                        A[(size_t)g * DIM + c] = v;
                    } else {
                        // interleaved BM: [head][16 B | 16 M]
                        size_t o = (size_t)g * 256 + (size_t)((c >> 4) * 32)
                                 + (c & 15) + (nt == 2 ? 16 : 0);
                        BM[o] = f2b(v);
                    }
                }
            }
        }
    }
}

// ---------------------------------------------------------------------------
// K5: segment loop, lane-local PV. One wave per relation, 16-edge tiles
// (2 edges per lane). Lane (el,hd) computes p(edge el, head hd) AND owns
// output dims [hd*16, hd*16+16): acc[16] += p * M[t][hd*16+j]. No shfl in
// the loop; one 48-shfl tree reduction over el in the epilogue. Per-edge
// data (B for score, M for PV) is one contiguous 64 B BM chunk per lane.
// ---------------------------------------------------------------------------
__global__ __launch_bounds__(256, 4) void k_segment(
    const float* __restrict__ A, const u16* __restrict__ BM,
    const void* __restrict__ attn_bin, const void* __restrict__ attn_vec,
    const int* __restrict__ cnt, const int* __restrict__ bucket,
    const int* __restrict__ trip, const void* __restrict__ emb,
    void* __restrict__ out)
{
    __shared__ float sAr[4][DIM];
    __shared__ float sVec[DIM];
    __shared__ float sBin[NUM_BIN * NUM_HEAD];
    __shared__ int sF[2];

    const int tid  = threadIdx.x;
    detect_flags(trip, (const u16*)emb, sF, tid);
    const int f32m = sF[1];

    const int wid  = tid >> 6, lane = tid & 63;
    const int r = blockIdx.x * 4 + wid;
    int nE = cnt[r * CNT_STR]; if (nE > CAP) nE = CAP;
    const int* __restrict__ bk = bucket + r * CAP;

    {
        const float2* ap = (const float2*)(A + (size_t)r * DIM);
        float2 a2 = ap[lane];
        sAr[wid][2 * lane] = a2.x; sAr[wid][2 * lane + 1] = a2.y;
    }
    if (tid < DIM) sVec[tid] = ldf(attn_vec, f32m, tid);
    else if (tid < DIM + NUM_BIN * NUM_HEAD)
        sBin[tid - DIM] = lrelu(ldf(attn_bin, f32m, tid - DIM));
    __syncthreads();

    if (nE == 0) {
        if (f32m) ((float2*)out)[(size_t)r * 64 + lane] = make_float2(0.f, 0.f);
        else      ((u32*)out)[(size_t)r * 64 + lane] = 0;
        return;
    }

    const int el = lane >> 3, hd = lane & 7;

    float av[16], vv[16];
    {
        const float4* pA = (const float4*)(&sAr[wid][hd * DIM_HID]);
        const float4* pV = (const float4*)(&sVec[hd * DIM_HID]);
        #pragma unroll
        for (int i = 0; i < 4; ++i) {
            float4 a4 = pA[i], v4 = pV[i];
            av[4*i+0]=a4.x; av[4*i+1]=a4.y; av[4*i+2]=a4.z; av[4*i+3]=a4.w;
            vv[4*i+0]=v4.x; vv[4*i+1]=v4.y; vv[4*i+2]=v4.z; vv[4*i+3]=v4.w;
        }
    }

    // lane's 64 B chunk base within a BM row: head hd -> offset hd*32 u16
    const u16* __restrict__ BMh = BM + hd * 32;

    // ---- pipeline prologue: tile-0 bucket entries + B-parts ----
    int tba = (el      < nE) ? bk[el]     : 0;
    int tbb = (8 + el  < nE) ? bk[8 + el] : 0;
    int ia = tba & 0xFFFFF, ib = tbb & 0xFFFFF;
    uint4 qa0, qa1, qb0, qb1;
    {
        const uint4* Ba = (const uint4*)(BMh + (size_t)ia * 256);
        const uint4* Bc = (const uint4*)(BMh + (size_t)ib * 256);
        qa0 = Ba[0]; qa1 = Ba[1];
        qb0 = Bc[0]; qb1 = Bc[1];
    }

    float l = 0.f;
    float acc[16];
    #pragma unroll
    for (int j = 0; j < 16; ++j) acc[j] = 0.f;

    for (int base = 0; base < nE; base += 16) {
        // ---- issue current tile's M loads (used after score) ----
        uint4 ma0, ma1, mb0, mb1;
        {
            const uint4* Ma = (const uint4*)(BMh + (size_t)ia * 256 + 16);
            const uint4* Mc = (const uint4*)(BMh + (size_t)ib * 256 + 16);
            ma0 = Ma[0]; ma1 = Ma[1];
            mb0 = Mc[0]; mb1 = Mc[1];
        }
        const int bsa = (tba >> 20) & 0xF;
        const int bsb = (tbb >> 20) & 0xF;

        // ---- prefetch next tile's bucket entries + B-parts ----
        int ea_n  = base + 16 + el;
        int eb_n  = base + 24 + el;
        int tba_n = (ea_n < nE) ? bk[ea_n] : 0;
        int tbb_n = (eb_n < nE) ? bk[eb_n] : 0;
        int ia_n  = tba_n & 0xFFFFF, ib_n = tbb_n & 0xFFFFF;
        uint4 qa0n, qa1n, qb0n, qb1n;
        {
            const uint4* Ban = (const uint4*)(BMh + (size_t)ia_n * 256);
            const uint4* Bcn = (const uint4*)(BMh + (size_t)ib_n * 256);
            qa0n = Ban[0]; qa1n = Ban[1];
            qb0n = Bcn[0]; qb1n = Bcn[1];
        }

        // ---- scores: 8 interleaved FMA chains (4 per edge) ----
        float sa0 = sBin[bsa * NUM_HEAD + hd];
        float sb0 = sBin[bsb * NUM_HEAD + hd];
        sa0 = fmaf(lrelu(av[0]  + lo2f(qa0.x)), vv[0],  sa0);
        sb0 = fmaf(lrelu(av[0]  + lo2f(qb0.x)), vv[0],  sb0);
        float sa1 = lrelu(av[1] + hi2f(qa0.x)) * vv[1];
        float sb1 = lrelu(av[1] + hi2f(qb0.x)) * vv[1];
        float sa2 = lrelu(av[2] + lo2f(qa0.y)) * vv[2];
        float sb2 = lrelu(av[2] + lo2f(qb0.y)) * vv[2];
        float sa3 = lrelu(av[3] + hi2f(qa0.y)) * vv[3];
        float sb3 = lrelu(av[3] + hi2f(qb0.y)) * vv[3];
        sa0 = fmaf(lrelu(av[4]  + lo2f(qa0.z)), vv[4],  sa0);
        sb0 = fmaf(lrelu(av[4]  + lo2f(qb0.z)), vv[4],  sb0);
        sa1 = fmaf(lrelu(av[5]  + hi2f(qa0.z)), vv[5],  sa1);
        sb1 = fmaf(lrelu(av[5]  + hi2f(qb0.z)), vv[5],  sb1);
        sa2 = fmaf(lrelu(av[6]  + lo2f(qa0.w)), vv[6],  sa2);
        sb2 = fmaf(lrelu(av[6]  + lo2f(qb0.w)), vv[6],  sb2);
        sa3 = fmaf(lrelu(av[7]  + hi2f(qa0.w)), vv[7],  sa3);
        sb3 = fmaf(lrelu(av[7]  + hi2f(qb0.w)), vv[7],  sb3);
        sa0 = fmaf(lrelu(av[8]  + lo2f(qa1.x)), vv[8],  sa0);
        sb0 = fmaf(lrelu(av[8]  + lo2f(qb1.x)), vv[8],  sb0);
        sa1 = fmaf(lrelu(av[9]  + hi2f(qa1.x)), vv[9],  sa1);
        sb1 = fmaf(lrelu(av[9]  + hi2f(qb1.x)), vv[9],  sb1);
        sa2 = fmaf(lrelu(av[10] + lo2f(qa1.y)), vv[10], sa2);
        sb2 = fmaf(lrelu(av[10] + lo2f(qb1.y)), vv[10], sb2);
        sa3 = fmaf(lrelu(av[11] + hi2f(qa1.y)), vv[11], sa3);
        sb3 = fmaf(lrelu(av[11] + hi2f(qb1.y)), vv[11], sb3);
        sa0 = fmaf(lrelu(av[12] + lo2f(qa1.z)), vv[12], sa0);
        sb0 = fmaf(lrelu(av[12] + lo2f(qb1.z)), vv[12], sb0);
        sa1 = fmaf(lrelu(av[13] + hi2f(qa1.z)), vv[13], sa1);
        sb1 = fmaf(lrelu(av[13] + hi2f(qb1.z)), vv[13], sb1);
        sa2 = fmaf(lrelu(av[14] + lo2f(qa1.w)), vv[14], sa2);
        sb2 = fmaf(lrelu(av[14] + lo2f(qb1.w)), vv[14], sb2);
        sa3 = fmaf(lrelu(av[15] + hi2f(qa1.w)), vv[15], sa3);
        sb3 = fmaf(lrelu(av[15] + hi2f(qb1.w)), vv[15], sb3);
        float sa = (sa0 + sa1) + (sa2 + sa3);
        float sb = (sb0 + sb1) + (sb2 + sb3);
        sa = fminf(fmaxf(sa, -60.f), 60.f);
        sb = fminf(fmaxf(sb, -60.f), 60.f);
        float pa = ((base + el)     < nE) ? __expf(sa) : 0.f;
        float pb = ((base + 8 + el) < nE) ? __expf(sb) : 0.f;
        l += pa + pb;

        // ---- PV: lane-local, no shfl ----
        {
            const u32* wa = (const u32*)&ma0;
            const u32* wb = (const u32*)&mb0;
            #pragma unroll
            for (int j = 0; j < 4; ++j) {
                acc[2*j]   = fmaf(pa, lo2f(wa[j]), acc[2*j]);
                acc[2*j+1] = fmaf(pa, hi2f(wa[j]), acc[2*j+1]);
                acc[2*j]   = fmaf(pb, lo2f(wb[j]), acc[2*j]);
                acc[2*j+1] = fmaf(pb, hi2f(wb[j]), acc[2*j+1]);
            }
            const u32* xa = (const u32*)&ma1;
            const u32* xb = (const u32*)&mb1;
            #pragma unroll
            for (int j = 0; j < 4; ++j) {
                acc[8+2*j]   = fmaf(pa, lo2f(xa[j]), acc[8+2*j]);
                acc[8+2*j+1] = fmaf(pa, hi2f(xa[j]), acc[8+2*j+1]);
                acc[8+2*j]   = fmaf(pb, lo2f(xb[j]), acc[8+2*j]);
                acc[8+2*j+1] = fmaf(pb, hi2f(xb[j]), acc[8+2*j+1]);
            }
        }

        // ---- rotate pipeline ----
        tba = tba_n; tbb = tbb_n; ia = ia_n; ib = ib_n;
        qa0 = qa0n; qa1 = qa1n; qb0 = qb0n; qb1 = qb1n;
    }

    // ---- epilogue: reduce over el lanes (same hd), normalize, store ----
    float lt = l + __shfl_xor(l, 8);
    lt += __shfl_xor(lt, 16);
    lt += __shfl_xor(lt, 32);
    float inv = 1.0f / (lt + 1e-16f);

    #pragma unroll
    for (int j = 0; j < 16; ++j) {
        float v = acc[j];
        v += __shfl_xor(v, 8);
        v += __shfl_xor(v, 16);
        v += __shfl_xor(v, 32);
        acc[j] = v * inv;
    }

    if (el == 0) {
        if (f32m) {
            float* op = (float*)out + (size_t)r * DIM + hd * DIM_HID;
            #pragma unroll
            for (int j = 0; j < 4; ++j) {
                float4 v4 = make_float4(acc[4*j], acc[4*j+1], acc[4*j+2], acc[4*j+3]);
                ((float4*)op)[j] = v4;
            }
        } else {
            u32* op = (u32*)out + (size_t)r * 64 + hd * 8;
            #pragma unroll
            for (int j = 0; j < 8; ++j)
                op[j] = pk2(acc[2*j], acc[2*j+1]);
        }
    }
}

// ---------------------------------------------------------------------------
extern "C" void kernel_launch(void* const* d_in, const int* in_sizes, int n_in,
                              void* d_out, int out_size, void* d_ws, size_t ws_size,
                              hipStream_t stream)
{
    (void)in_sizes; (void)n_in; (void)out_size; (void)ws_size;
    const void* emb      = d_in[0];
    const int*  trip     = (const int*)d_in[1];
    const void* w_attn   = d_in[2];
    const void* b_attn   = d_in[3];
    const void* attn_bin = d_in[4];
    const void* attn_vec = d_in[5];
    const void* w_aggr   = d_in[6];
    const void* b_aggr   = d_in[7];

    // workspace carve (~32.0 MB)
    char* p = (char*)d_ws;
    float* A      = (float*)p; p += (size_t)NUM_REL * DIM * 4;          // 10.24 MB
    u16*   BM     = (u16*)p;   p += (size_t)NUM_REL * 256 * 2;          // 10.24 MB
    int*   bucket = (int*)p;   p += (size_t)NUM_REL * CAP * 4;          // 10.24 MB
    int*   cnt    = (int*)p;   p += (size_t)NUM_REL * CNT_STR * 4;      //  1.28 MB

    hipMemsetAsync(cnt, 0, (size_t)NUM_REL * CNT_STR * sizeof(int), stream);
    k_projscatter<<<PROJ_BLKS + SCAT_BLKS, 256, 0, stream>>>(
        emb, trip, w_attn, w_aggr, b_attn, b_aggr, A, BM, cnt, bucket);
    k_segment<<<NUM_REL / 4, 256, 0, stream>>>(A, BM, attn_bin, attn_vec,
                                               cnt, bucket, trip, emb, d_out);
}

// Round 6
// 161.393 us; speedup vs baseline: 1.0496x; 1.0128x over previous
//
#include <hip/hip_runtime.h>
#include <hip/hip_bf16.h>
#include <cstdint>
#include <cstddef>

#define NUM_REL    20000
#define NUM_EDGES  640000
#define DIM        128
#define NUM_HEAD   8
#define DIM_HID    16
#define NUM_BIN    10
#define CAP        128            // bucket capacity (P(overflow) ~ 4e-13)
#define CNT_STR    16             // cnt padded: 1 counter per 64B line
#define PROJ_BLKS  471            // 157 M-tiles x 3 output matrices
#define SCAT_BLKS  625            // 625*256*4 = 640000 edges, 4 per thread
#define PREP_BLKS  1250           // 1250*256 threads: 8 elems cast + 1 cnt zero

using u16 = unsigned short;
using u32 = unsigned int;
typedef __attribute__((ext_vector_type(8))) short bf16x8;
typedef __attribute__((ext_vector_type(4))) float f32x4;

__device__ __forceinline__ float b2f(u16 u) { return __uint_as_float(((u32)u) << 16); }
__device__ __forceinline__ float lo2f(u32 u) { return __uint_as_float(u << 16); }
__device__ __forceinline__ float hi2f(u32 u) { return __uint_as_float(u & 0xffff0000u); }
__device__ __forceinline__ float lrelu(float x) { return fmaxf(x, 0.2f * x); }
__device__ __forceinline__ int clampi(int v, int hi) { return v < 0 ? 0 : (v > hi ? hi : v); }
__device__ __forceinline__ float ldf(const void* p, int f32m, int i)
{ return f32m ? ((const float*)p)[i] : b2f(((const u16*)p)[i]); }
__device__ __forceinline__ u16 f2b(float x)
{ u32 u = __float_as_uint(x); u += 0x7fffu + ((u >> 16) & 1u); return (u16)(u >> 16); }
__device__ __forceinline__ u32 pk2(float a, float b)
{ return (u32)f2b(a) | ((u32)f2b(b) << 16); }

// ---------------------------------------------------------------------------
// Per-block layout detection (proven logic, block-local). Deterministic
// inputs -> all blocks agree. sF[0]=is64, sF[1]=f32m.
// ---------------------------------------------------------------------------
__device__ __forceinline__ void detect_flags(const int* __restrict__ trip,
                                             const u16* __restrict__ emb,
                                             int* sF, int tid)
{
    if (tid < 64) {
        bool odd_zero = (trip[2 * tid + 1] == 0) && (trip[2 * tid + 129] == 0);
        unsigned long long m1 = __ballot(odd_zero);
        int ex = (emb[2 * tid] >> 7) & 0xFF;
        bool inr = (ex >= 110) && (ex <= 136);
        unsigned long long m2 = __ballot(inr);
        if (tid == 0) {
            sF[0] = (~m1 == 0ull) ? 1 : 0;
            sF[1] = (__popcll(m2) >= 32) ? 0 : 1;   // few in-range => fp32
        }
    }
    __syncthreads();
}

// ---------------------------------------------------------------------------
// K0: prep. Casts emb -> bf16 Eb (RNE, identical numerics to the previous
// inline pk2 path) and zeroes cnt (exactly one int per thread: 320000).
// Removes the f32->bf16 convert chain + double-width loads from k_proj's
// A-fragment path, and replaces the hipMemsetAsync launch.
// ---------------------------------------------------------------------------
__global__ __launch_bounds__(256) void k_prep(
    const void* __restrict__ emb, const int* __restrict__ trip,
    u16* __restrict__ Eb, int* __restrict__ cnt)
{
    __shared__ int sF[2];
    const int tid = threadIdx.x;
    detect_flags(trip, (const u16*)emb, sF, tid);
    const int f32m = sF[1];

    const int g = blockIdx.x * 256 + tid;    // [0, 320000)
    cnt[g] = 0;
    if (f32m) {
        const float4* src = (const float4*)emb;
        float4 x0 = src[2 * g], x1 = src[2 * g + 1];
        uint4 o;
        o.x = pk2(x0.x, x0.y); o.y = pk2(x0.z, x0.w);
        o.z = pk2(x1.x, x1.y); o.w = pk2(x1.z, x1.w);
        ((uint4*)Eb)[g] = o;
    } else {
        ((uint4*)Eb)[g] = ((const uint4*)emb)[g];
    }
}

// ---------------------------------------------------------------------------
// K1: fused [MFMA projections (blocks 0..470)] || [bucket scatter (471+)].
// Split-K W staging (16 KB LDS). nt=0: A=emb@Wa1^T (fp32);
// nt=1: B-half of BM (emb@Wa2^T+b, bf16); nt=2: M-half of BM (emb@Wg^T+b).
// A-fragments now load bf16 directly from Eb (no cvt chain, half the bytes).
// BM row layout: [head][16 B-dims | 16 M-dims] -> 512 B/row.
// Scatter: 4 edges/thread, vectorized triplet loads (overlaps with proj).
// ---------------------------------------------------------------------------
__global__ __launch_bounds__(256) void k_projscatter(
    const u16* __restrict__ Eb, const int* __restrict__ trip,
    const void* __restrict__ emb,
    const void* __restrict__ w_attn, const void* __restrict__ w_aggr,
    const void* __restrict__ b_attn, const void* __restrict__ b_aggr,
    float* __restrict__ A, u16* __restrict__ BM,
    int* __restrict__ cnt, int* __restrict__ bucket)
{
    __shared__ u16 sW[128 * 64];     // 16 KB (one 64-wide K half)
    __shared__ float sBias[128];
    __shared__ int sF[2];

    const int tid = threadIdx.x;
    detect_flags(trip, (const u16*)emb, sF, tid);
    const int is64 = sF[0], f32m = sF[1];

    if (blockIdx.x >= PROJ_BLKS) {
        // ---------------- scatter: 4 edges per thread ----------------
        const int e0 = ((blockIdx.x - PROJ_BLKS) * 256 + tid) * 4;
        int h[4], t[4], b[4], p[4];
        if (is64) {
            const int4* w = (const int4*)(trip + 6 * e0);
            int4 w0 = w[0], w1 = w[1], w2 = w[2], w3 = w[3], w4 = w[4], w5 = w[5];
            h[0] = w0.x; t[0] = w0.z; b[0] = w1.x;
            h[1] = w1.z; t[1] = w2.x; b[1] = w2.z;
            h[2] = w3.x; t[2] = w3.z; b[2] = w4.x;
            h[3] = w4.z; t[3] = w5.x; b[3] = w5.z;
        } else {
            const int4* w = (const int4*)(trip + 3 * e0);
            int4 w0 = w[0], w1 = w[1], w2 = w[2];
            h[0] = w0.x; t[0] = w0.y; b[0] = w0.z;
            h[1] = w0.w; t[1] = w1.x; b[1] = w1.y;
            h[2] = w1.z; t[2] = w1.w; b[2] = w2.x;
            h[3] = w2.y; t[3] = w2.z; b[3] = w2.w;
        }
        #pragma unroll
        for (int i = 0; i < 4; ++i) {
            h[i] = clampi(h[i], NUM_REL - 1);
            t[i] = clampi(t[i], NUM_REL - 1);
            b[i] = clampi(b[i], NUM_BIN - 1);
        }
        #pragma unroll
        for (int i = 0; i < 4; ++i) p[i] = atomicAdd(&cnt[h[i] * CNT_STR], 1);
        #pragma unroll
        for (int i = 0; i < 4; ++i)
            if (p[i] < CAP) bucket[h[i] * CAP + p[i]] = t[i] | (b[i] << 20);
        return;
    }

    // ---------------- projection tile ----------------
    const int mt = blockIdx.x / 3, nt = blockIdx.x % 3;
    const int r0 = mt * 128;

    if (tid < 128)
        sBias[tid] = (nt == 0) ? 0.f : ldf((nt == 1) ? b_attn : b_aggr, f32m, tid);

    const void* wsrc = (nt == 2) ? w_aggr : w_attn;
    const int stride = (nt == 2) ? 128 : 256;
    const int koff   = (nt == 1) ? 128 : 0;

    const int lane = tid & 63, wid = tid >> 6;
    const int wm = (wid >> 1) * 64, wn = (wid & 1) * 64;
    const int ln15 = lane & 15, q = lane >> 4;

    // A-frag source rows (clamped; epilogue guards the stores)
    int arow[4];
    #pragma unroll
    for (int mi = 0; mi < 4; ++mi) {
        int g = r0 + wm + mi * 16 + ln15;
        arow[mi] = (g < NUM_REL) ? g : (NUM_REL - 1);
    }

    f32x4 acc[4][4] = {};
    #pragma unroll
    for (int kh = 0; kh < 2; ++kh) {
        if (kh) __syncthreads();      // all reads of previous half done
        // stage K-half [kh*64, kh*64+64) for all 128 output rows
        if (f32m) {
            const float* src = (const float*)wsrc;
            #pragma unroll
            for (int i = 0; i < 8; ++i) {
                int f = i * 256 + tid;
                int row = f >> 4, pos = f & 15;   // float4 index within half
                const float* rp = src + (size_t)row * stride + koff + kh * 64;
                float4 x = ((const float4*)rp)[pos];
                int chunk = (pos >> 1) ^ (row & 7);
                *(uint2*)&sW[row * 64 + chunk * 8 + (pos & 1) * 4] =
                    make_uint2(pk2(x.x, x.y), pk2(x.z, x.w));
            }
        } else {
            const u16* src = (const u16*)wsrc;
            #pragma unroll
            for (int i = 0; i < 4; ++i) {
                int f = i * 256 + tid;
                int row = f >> 3, pos = f & 7;    // uint4 index within half
                const u16* rp = src + (size_t)row * stride + koff + kh * 64;
                uint4 x = ((const uint4*)rp)[pos];
                int chunk = pos ^ (row & 7);
                *(uint4*)&sW[row * 64 + chunk * 8] = x;
            }
        }
        __syncthreads();

        #pragma unroll
        for (int k2 = 0; k2 < 2; ++k2) {
            const int kkg = kh * 2 + k2;
            const int kc = (kkg * 4 + q) * 8;         // element offset in K
            const int cl = (k2 * 4 + q) ^ (ln15 & 7); // swizzled local chunk
            bf16x8 a[4], b[4];
            #pragma unroll
            for (int mi = 0; mi < 4; ++mi)
                a[mi] = *(const bf16x8*)(Eb + (size_t)arow[mi] * DIM + kc);
            #pragma unroll
            for (int ni = 0; ni < 4; ++ni) {
                int n = wn + ni * 16 + ln15;
                b[ni] = *(const bf16x8*)&sW[n * 64 + cl * 8];
            }
            #pragma unroll
            for (int mi = 0; mi < 4; ++mi)
                #pragma unroll
                for (int ni = 0; ni < 4; ++ni)
                    acc[mi][ni] = __builtin_amdgcn_mfma_f32_16x16x32_bf16(
                        a[mi], b[ni], acc[mi][ni], 0, 0, 0);
        }
    }

    #pragma unroll
    for (int mi = 0; mi < 4; ++mi) {
        #pragma unroll
        for (int reg = 0; reg < 4; ++reg) {
            int g = r0 + wm + mi * 16 + q * 4 + reg;
            if (g < NUM_REL) {
                #pragma unroll
                for (int ni = 0; ni < 4; ++ni) {
                    int c = wn + ni * 16 + ln15;
                    float v = acc[mi][ni][reg] + sBias[c];
                    if (nt == 0) {
                        A[(size_t)g * DIM + c] = v;
                    } else {
                        // interleaved BM: [head][16 B | 16 M]
                        size_t o = (size_t)g * 256 + (size_t)((c >> 4) * 32)
                                 + (c & 15) + (nt == 2 ? 16 : 0);
                        BM[o] = f2b(v);
                    }
                }
            }
        }
    }
}

// ---------------------------------------------------------------------------
// K5: segment loop, lane-local PV. One wave per relation, 16-edge tiles
// (2 edges per lane). Lane (el,hd) computes p(edge el, head hd) AND owns
// output dims [hd*16, hd*16+16): acc[16] += p * M[t][hd*16+j]. No shfl in
// the loop; one 48-shfl tree reduction over el in the epilogue. Per-edge
// data (B for score, M for PV) is one contiguous 64 B BM chunk per lane.
// ---------------------------------------------------------------------------
__global__ __launch_bounds__(256, 4) void k_segment(
    const float* __restrict__ A, const u16* __restrict__ BM,
    const void* __restrict__ attn_bin, const void* __restrict__ attn_vec,
    const int* __restrict__ cnt, const int* __restrict__ bucket,
    const int* __restrict__ trip, const void* __restrict__ emb,
    void* __restrict__ out)
{
    __shared__ float sAr[4][DIM];
    __shared__ float sVec[DIM];
    __shared__ float sBin[NUM_BIN * NUM_HEAD];
    __shared__ int sF[2];

    const int tid  = threadIdx.x;
    detect_flags(trip, (const u16*)emb, sF, tid);
    const int f32m = sF[1];

    const int wid  = tid >> 6, lane = tid & 63;
    const int r = blockIdx.x * 4 + wid;
    int nE = cnt[r * CNT_STR]; if (nE > CAP) nE = CAP;
    const int* __restrict__ bk = bucket + r * CAP;

    {
        const float2* ap = (const float2*)(A + (size_t)r * DIM);
        float2 a2 = ap[lane];
        sAr[wid][2 * lane] = a2.x; sAr[wid][2 * lane + 1] = a2.y;
    }
    if (tid < DIM) sVec[tid] = ldf(attn_vec, f32m, tid);
    else if (tid < DIM + NUM_BIN * NUM_HEAD)
        sBin[tid - DIM] = lrelu(ldf(attn_bin, f32m, tid - DIM));
    __syncthreads();

    if (nE == 0) {
        if (f32m) ((float2*)out)[(size_t)r * 64 + lane] = make_float2(0.f, 0.f);
        else      ((u32*)out)[(size_t)r * 64 + lane] = 0;
        return;
    }

    const int el = lane >> 3, hd = lane & 7;

    float av[16], vv[16];
    {
        const float4* pA = (const float4*)(&sAr[wid][hd * DIM_HID]);
        const float4* pV = (const float4*)(&sVec[hd * DIM_HID]);
        #pragma unroll
        for (int i = 0; i < 4; ++i) {
            float4 a4 = pA[i], v4 = pV[i];
            av[4*i+0]=a4.x; av[4*i+1]=a4.y; av[4*i+2]=a4.z; av[4*i+3]=a4.w;
            vv[4*i+0]=v4.x; vv[4*i+1]=v4.y; vv[4*i+2]=v4.z; vv[4*i+3]=v4.w;
        }
    }

    // lane's 64 B chunk base within a BM row: head hd -> offset hd*32 u16
    const u16* __restrict__ BMh = BM + hd * 32;

    // ---- pipeline prologue: tile-0 bucket entries + B-parts ----
    int tba = (el      < nE) ? bk[el]     : 0;
    int tbb = (8 + el  < nE) ? bk[8 + el] : 0;
    int ia = tba & 0xFFFFF, ib = tbb & 0xFFFFF;
    uint4 qa0, qa1, qb0, qb1;
    {
        const uint4* Ba = (const uint4*)(BMh + (size_t)ia * 256);
        const uint4* Bc = (const uint4*)(BMh + (size_t)ib * 256);
        qa0 = Ba[0]; qa1 = Ba[1];
        qb0 = Bc[0]; qb1 = Bc[1];
    }

    float l = 0.f;
    float acc[16];
    #pragma unroll
    for (int j = 0; j < 16; ++j) acc[j] = 0.f;

    for (int base = 0; base < nE; base += 16) {
        // ---- issue current tile's M loads (used after score) ----
        uint4 ma0, ma1, mb0, mb1;
        {
            const uint4* Ma = (const uint4*)(BMh + (size_t)ia * 256 + 16);
            const uint4* Mc = (const uint4*)(BMh + (size_t)ib * 256 + 16);
            ma0 = Ma[0]; ma1 = Ma[1];
            mb0 = Mc[0]; mb1 = Mc[1];
        }
        const int bsa = (tba >> 20) & 0xF;
        const int bsb = (tbb >> 20) & 0xF;

        // ---- prefetch next tile's bucket entries + B-parts ----
        int ea_n  = base + 16 + el;
        int eb_n  = base + 24 + el;
        int tba_n = (ea_n < nE) ? bk[ea_n] : 0;
        int tbb_n = (eb_n < nE) ? bk[eb_n] : 0;
        int ia_n  = tba_n & 0xFFFFF, ib_n = tbb_n & 0xFFFFF;
        uint4 qa0n, qa1n, qb0n, qb1n;
        {
            const uint4* Ban = (const uint4*)(BMh + (size_t)ia_n * 256);
            const uint4* Bcn = (const uint4*)(BMh + (size_t)ib_n * 256);
            qa0n = Ban[0]; qa1n = Ban[1];
            qb0n = Bcn[0]; qb1n = Bcn[1];
        }

        // ---- scores: 8 interleaved FMA chains (4 per edge) ----
        float sa0 = sBin[bsa * NUM_HEAD + hd];
        float sb0 = sBin[bsb * NUM_HEAD + hd];
        sa0 = fmaf(lrelu(av[0]  + lo2f(qa0.x)), vv[0],  sa0);
        sb0 = fmaf(lrelu(av[0]  + lo2f(qb0.x)), vv[0],  sb0);
        float sa1 = lrelu(av[1] + hi2f(qa0.x)) * vv[1];
        float sb1 = lrelu(av[1] + hi2f(qb0.x)) * vv[1];
        float sa2 = lrelu(av[2] + lo2f(qa0.y)) * vv[2];
        float sb2 = lrelu(av[2] + lo2f(qb0.y)) * vv[2];
        float sa3 = lrelu(av[3] + hi2f(qa0.y)) * vv[3];
        float sb3 = lrelu(av[3] + hi2f(qb0.y)) * vv[3];
        sa0 = fmaf(lrelu(av[4]  + lo2f(qa0.z)), vv[4],  sa0);
        sb0 = fmaf(lrelu(av[4]  + lo2f(qb0.z)), vv[4],  sb0);
        sa1 = fmaf(lrelu(av[5]  + hi2f(qa0.z)), vv[5],  sa1);
        sb1 = fmaf(lrelu(av[5]  + hi2f(qb0.z)), vv[5],  sb1);
        sa2 = fmaf(lrelu(av[6]  + lo2f(qa0.w)), vv[6],  sa2);
        sb2 = fmaf(lrelu(av[6]  + lo2f(qb0.w)), vv[6],  sb2);
        sa3 = fmaf(lrelu(av[7]  + hi2f(qa0.w)), vv[7],  sa3);
        sb3 = fmaf(lrelu(av[7]  + hi2f(qb0.w)), vv[7],  sb3);
        sa0 = fmaf(lrelu(av[8]  + lo2f(qa1.x)), vv[8],  sa0);
        sb0 = fmaf(lrelu(av[8]  + lo2f(qb1.x)), vv[8],  sb0);
        sa1 = fmaf(lrelu(av[9]  + hi2f(qa1.x)), vv[9],  sa1);
        sb1 = fmaf(lrelu(av[9]  + hi2f(qb1.x)), vv[9],  sb1);
        sa2 = fmaf(lrelu(av[10] + lo2f(qa1.y)), vv[10], sa2);
        sb2 = fmaf(lrelu(av[10] + lo2f(qb1.y)), vv[10], sb2);
        sa3 = fmaf(lrelu(av[11] + hi2f(qa1.y)), vv[11], sa3);
        sb3 = fmaf(lrelu(av[11] + hi2f(qb1.y)), vv[11], sb3);
        sa0 = fmaf(lrelu(av[12] + lo2f(qa1.z)), vv[12], sa0);
        sb0 = fmaf(lrelu(av[12] + lo2f(qb1.z)), vv[12], sb0);
        sa1 = fmaf(lrelu(av[13] + hi2f(qa1.z)), vv[13], sa1);
        sb1 = fmaf(lrelu(av[13] + hi2f(qb1.z)), vv[13], sb1);
        sa2 = fmaf(lrelu(av[14] + lo2f(qa1.w)), vv[14], sa2);
        sb2 = fmaf(lrelu(av[14] + lo2f(qb1.w)), vv[14], sb2);
        sa3 = fmaf(lrelu(av[15] + hi2f(qa1.w)), vv[15], sa3);
        sb3 = fmaf(lrelu(av[15] + hi2f(qb1.w)), vv[15], sb3);
        float sa = (sa0 + sa1) + (sa2 + sa3);
        float sb = (sb0 + sb1) + (sb2 + sb3);
        sa = fminf(fmaxf(sa, -60.f), 60.f);
        sb = fminf(fmaxf(sb, -60.f), 60.f);
        float pa = ((base + el)     < nE) ? __expf(sa) : 0.f;
        float pb = ((base + 8 + el) < nE) ? __expf(sb) : 0.f;
        l += pa + pb;

        // ---- PV: lane-local, no shfl ----
        {
            const u32* wa = (const u32*)&ma0;
            const u32* wb = (const u32*)&mb0;
            #pragma unroll
            for (int j = 0; j < 4; ++j) {
                acc[2*j]   = fmaf(pa, lo2f(wa[j]), acc[2*j]);
                acc[2*j+1] = fmaf(pa, hi2f(wa[j]), acc[2*j+1]);
                acc[2*j]   = fmaf(pb, lo2f(wb[j]), acc[2*j]);
                acc[2*j+1] = fmaf(pb, hi2f(wb[j]), acc[2*j+1]);
            }
            const u32* xa = (const u32*)&ma1;
            const u32* xb = (const u32*)&mb1;
            #pragma unroll
            for (int j = 0; j < 4; ++j) {
                acc[8+2*j]   = fmaf(pa, lo2f(xa[j]), acc[8+2*j]);
                acc[8+2*j+1] = fmaf(pa, hi2f(xa[j]), acc[8+2*j+1]);
                acc[8+2*j]   = fmaf(pb, lo2f(xb[j]), acc[8+2*j]);
                acc[8+2*j+1] = fmaf(pb, hi2f(xb[j]), acc[8+2*j+1]);
            }
        }

        // ---- rotate pipeline ----
        tba = tba_n; tbb = tbb_n; ia = ia_n; ib = ib_n;
        qa0 = qa0n; qa1 = qa1n; qb0 = qb0n; qb1 = qb1n;
    }

    // ---- epilogue: reduce over el lanes (same hd), normalize, store ----
    float lt = l + __shfl_xor(l, 8);
    lt += __shfl_xor(lt, 16);
    lt += __shfl_xor(lt, 32);
    float inv = 1.0f / (lt + 1e-16f);

    #pragma unroll
    for (int j = 0; j < 16; ++j) {
        float v = acc[j];
        v += __shfl_xor(v, 8);
        v += __shfl_xor(v, 16);
        v += __shfl_xor(v, 32);
        acc[j] = v * inv;
    }

    if (el == 0) {
        if (f32m) {
            float* op = (float*)out + (size_t)r * DIM + hd * DIM_HID;
            #pragma unroll
            for (int j = 0; j < 4; ++j) {
                float4 v4 = make_float4(acc[4*j], acc[4*j+1], acc[4*j+2], acc[4*j+3]);
                ((float4*)op)[j] = v4;
            }
        } else {
            u32* op = (u32*)out + (size_t)r * 64 + hd * 8;
            #pragma unroll
            for (int j = 0; j < 8; ++j)
                op[j] = pk2(acc[2*j], acc[2*j+1]);
        }
    }
}

// ---------------------------------------------------------------------------
extern "C" void kernel_launch(void* const* d_in, const int* in_sizes, int n_in,
                              void* d_out, int out_size, void* d_ws, size_t ws_size,
                              hipStream_t stream)
{
    (void)in_sizes; (void)n_in; (void)out_size; (void)ws_size;
    const void* emb      = d_in[0];
    const int*  trip     = (const int*)d_in[1];
    const void* w_attn   = d_in[2];
    const void* b_attn   = d_in[3];
    const void* attn_bin = d_in[4];
    const void* attn_vec = d_in[5];
    const void* w_aggr   = d_in[6];
    const void* b_aggr   = d_in[7];

    // workspace carve (~37.1 MB)
    char* p = (char*)d_ws;
    float* A      = (float*)p; p += (size_t)NUM_REL * DIM * 4;          // 10.24 MB
    u16*   BM     = (u16*)p;   p += (size_t)NUM_REL * 256 * 2;          // 10.24 MB
    int*   bucket = (int*)p;   p += (size_t)NUM_REL * CAP * 4;          // 10.24 MB
    int*   cnt    = (int*)p;   p += (size_t)NUM_REL * CNT_STR * 4;      //  1.28 MB
    u16*   Eb     = (u16*)p;   p += (size_t)NUM_REL * DIM * 2;          //  5.12 MB

    k_prep<<<PREP_BLKS, 256, 0, stream>>>(emb, trip, Eb, cnt);
    k_projscatter<<<PROJ_BLKS + SCAT_BLKS, 256, 0, stream>>>(
        Eb, trip, emb, w_attn, w_aggr, b_attn, b_aggr, A, BM, cnt, bucket);
    k_segment<<<NUM_REL / 4, 256, 0, stream>>>(A, BM, attn_bin, attn_vec,
                                               cnt, bucket, trip, emb, d_out);
}